// Round 12
// baseline (111.796 us; speedup 1.0000x reference)
//
#include <hip/hip_runtime.h>
#include <math.h>

// BIMM2D: M=250000 points, P=4 interior phases, K=6 interface pairs, N_MC=64
#define KN 384            // K * N_MC table entries
#define TPB 256
#define PPB 128           // points per block (two half-waves per point)

typedef float v2f __attribute__((ext_vector_type(2)));

// Device-global scratch. g_ctr is module-init 0 and self-restored by the last
// block each launch -> graph-replay safe, independent of d_ws poison.
__device__ double g_part[2048];
__device__ int    g_ctr = 0;

__device__ __forceinline__ float fexp2(float x) {
  return __builtin_amdgcn_exp2f(x);   // native v_exp_f32
}

// R12: R7 structure + TWO levers aimed at the measured limiter (Occupancy
// pinned at 24% = ~2 waves/SIMD; R11 proved intra-wave scheduling is not it).
//  1) Split the 384-entry sum across two half-waves per point: 128 pts/block,
//     h = tid>>7 picks entries [h*192,(h+1)*192). Same total FLOPs, 2x waves
//     (7813 ~= 7.6/SIMD) -> dependency bubbles covered by TLP.
//  2) Packed math: (a1,a2) and the two accumulates done as v2f so the
//     backend emits v_pk_*_f32: per 2 entries 6 pk-VALU + 4 trans
//     (vs 12 VALU + 4 trans scalar).
// Halves combine via LDS (sS) with one barrier; h=1 threads do the log.
__global__ __launch_bounds__(TPB, 4) void fused_kernel(
    const float* __restrict__ u, const float* __restrict__ v,
    const float* __restrict__ eps, const float* __restrict__ I,
    const float* __restrict__ W, const float* __restrict__ sb_,
    const float* __restrict__ sn_, const float* __restrict__ d_,
    const float* __restrict__ r_, float* __restrict__ out,
    int M, int nb) {
  __shared__ __align__(16) float stx[KN], sty[KN], stz[KN];
  __shared__ float  sS[PPB];
  __shared__ double red[TPB];
  __shared__ int    slast;
  const int tid = threadIdx.x;
  const int pi  = tid & (PPB - 1);      // point slot within block
  const int h   = tid >> 7;             // entry-half: 0 -> [0,192), 1 -> [192,384)
  const int i   = blockIdx.x * PPB + pi;

  // hoist point load to overlap with the prelude (both halves load same point)
  float uu = 0.f, vv = 1.f;
  if (i < M) { uu = u[i]; vv = v[i]; }

  // ---- folded constants (uniform; float, faithful to f32 reference) ----
  const float sb  = sb_[0];
  const float sn  = sn_[0];
  const float dd  = d_[0];
  const float rho = tanhf(r_[0]);
  const float s2  = sn * sn * (1.f - rho);      // sr^2
  const float sr  = sqrtf(s2);
  const float isn = 1.f / sn;
  const float inv_s2 = 1.f / s2;
  const float LOG2E = 1.4426950408889634f;
  const float SQH   = sqrtf(0.5f * LOG2E);      // sqrt(0.5*log2 e)

  float wmax = W[0];
  for (int j = 1; j < 10; ++j) wmax = fmaxf(wmax, W[j]);
  float se = 0.f;
  for (int j = 0; j < 10; ++j) se += expf(W[j] - wmax);
  const float lse = wmax + logf(se);

  const float LOG2PI_ = 1.8378770664093453f;
  const float LOG2_   = 0.6931471805599453f;
  const float LGG32   = -0.12078223763524522f;  // log(gamma(1.5))
  const float LOGPI_  = 1.1447298858494002f;
  const float Cterm = -logf(sn) - 0.5f * LOG2PI_ - logf(sr) - 0.5f * LOGPI_;
  const float Cint0 = LOG2_ - LGG32 - 3.f * logf(sr) - logf(sn) - 0.5f * LOG2PI_;

  float wint[4], cq[4];
#pragma unroll
  for (int p = 0; p < 4; ++p) {
    wint[p] = expf(W[p] - lse + Cint0);
    cq[p]   = I[p] * isn * SQH;
  }

  // ---- per-(k,n) table into LDS (SoA, exp2-folded) ----
  // stx = In/sn*SQH, sty = (2G/s2)*log2e, stz = wk*exp(-G^2/s2)/G
  const int IAc[6] = {0, 0, 0, 1, 1, 2};
  const int IBc[6] = {1, 2, 3, 2, 3, 3};
  for (int t = tid; t < KN; t += TPB) {
    const int k = t >> 6;
    const float Ia = I[IAc[k]], Ib = I[IBc[k]];
    const float wk = expf(W[4 + k] - lse + Cterm) * (1.0f / 64.0f);
    const float e  = eps[t];
    const float x  = e * 2.f * dd * sb - dd * sb;
    const float y  = x / (1.4142135623730951f * sb);
    const float In = (erff(y) + 1.f) * 0.5f * (Ib - Ia) + Ia;
    const float qq = 2.f * (In - Ia) / (Ib - Ia) - 1.f;
    const float gi = erfinvf(qq);
    const float G  = (Ib - Ia) * 0.3989422804014327f / sb * expf(-gi * gi);
    stx[t] = In * isn * SQH;
    sty[t] = 2.f * inv_s2 * G * LOG2E;
    stz[t] = wk * expf(-G * G * inv_s2) / G;
  }

  // ---- per-thread point prelude ----
  // acc(point) = c1 + c0 * S,  S = sum over 384 entries of tz*(e1-e2)
  // c0 = v*g, c1 = v^2*g*aint, g = exp(-v^2/s2); pad points: c0=0, c1=1.
  const float us = uu * isn * SQH;
  const float gg = fexp2(-vv * vv * inv_s2 * LOG2E);
  float aint = 0.f;
#pragma unroll
  for (int p = 0; p < 4; ++p) {
    const float dq = us - cq[p];
    aint = fmaf(wint[p], fexp2(-dq * dq), aint);
  }
  const float c0 = (i < M) ? vv * gg : 0.f;
  const float c1 = (i < M) ? vv * vv * gg * aint : 1.f;

  __syncthreads();

  // ---- main loop: this half's 192 entries, packed v2f (v_pk_*_f32) ----
  const v2f us2 = {us, us};
  const v2f vv2 = {vv, vv};
  v2f SPa = {0.f, 0.f}, SMa = {0.f, 0.f};   // pair-0 accumulators (e1 / e2)
  v2f SPb = {0.f, 0.f}, SMb = {0.f, 0.f};   // pair-1 accumulators
  const float4* px = (const float4*)(stx + h * (KN / 2));   // 48 float4s
  const float4* py = (const float4*)(sty + h * (KN / 2));
  const float4* pz = (const float4*)(stz + h * (KN / 2));
#pragma unroll 4
  for (int j = 0; j < KN / 8; ++j) {      // 48 groups of 4 entries
    const float4 X = px[j], Y = py[j], Z = pz[j];
    {   // entries 4j, 4j+1
      const v2f tx2 = {X.x, X.y}, ty2 = {Y.x, Y.y}, tz2 = {Z.x, Z.y};
      const v2f du = us2 - tx2;
      const v2f nd = du * -du;
      const v2f a1 = __builtin_elementwise_fma(vv2,  ty2, nd);
      const v2f a2 = __builtin_elementwise_fma(vv2, -ty2, nd);
      v2f e1, e2;
      e1.x = fexp2(a1.x); e1.y = fexp2(a1.y);
      e2.x = fexp2(a2.x); e2.y = fexp2(a2.y);
      SPa = __builtin_elementwise_fma(tz2, e1, SPa);
      SMa = __builtin_elementwise_fma(tz2, e2, SMa);
    }
    {   // entries 4j+2, 4j+3
      const v2f tx2 = {X.z, X.w}, ty2 = {Y.z, Y.w}, tz2 = {Z.z, Z.w};
      const v2f du = us2 - tx2;
      const v2f nd = du * -du;
      const v2f a1 = __builtin_elementwise_fma(vv2,  ty2, nd);
      const v2f a2 = __builtin_elementwise_fma(vv2, -ty2, nd);
      v2f e1, e2;
      e1.x = fexp2(a1.x); e1.y = fexp2(a1.y);
      e2.x = fexp2(a2.x); e2.y = fexp2(a2.y);
      SPb = __builtin_elementwise_fma(tz2, e1, SPb);
      SMb = __builtin_elementwise_fma(tz2, e2, SMb);
    }
  }
  const float Shalf = ((SPa.x + SPa.y) + (SPb.x + SPb.y))
                    - ((SMa.x + SMa.y) + (SMb.x + SMb.y));

  // ---- combine halves via LDS; h=1 threads produce the per-point log ----
  if (h == 0) sS[pi] = Shalf;
  __syncthreads();
  double mysum = 0.0;
  if (h == 1) {
    const float S = sS[pi] + Shalf;
    mysum = (double)__logf(fmaf(c0, S, c1));   // pad points: log(1) = 0
  }

  // ---- block reduction (deterministic tree) ----
  red[tid] = mysum;
  __syncthreads();
  for (int s = TPB / 2; s > 0; s >>= 1) {
    if (tid < s) red[tid] += red[tid + s];
    __syncthreads();
  }
  if (tid == 0)
    __hip_atomic_store(&g_part[blockIdx.x], red[0], __ATOMIC_RELAXED,
                       __HIP_MEMORY_SCOPE_AGENT);

  // ---- last-block-done final reduction (fixed order -> deterministic) ----
  if (tid == 0) {
    const int c = __hip_atomic_fetch_add(&g_ctr, 1, __ATOMIC_ACQ_REL,
                                         __HIP_MEMORY_SCOPE_AGENT);
    slast = (c == nb - 1) ? 1 : 0;
  }
  __syncthreads();
  if (slast) {
    double s = 0.0;
    for (int j = tid; j < nb; j += TPB)
      s += __hip_atomic_load(&g_part[j], __ATOMIC_RELAXED,
                             __HIP_MEMORY_SCOPE_AGENT);
    red[tid] = s;
    __syncthreads();
    for (int k2 = TPB / 2; k2 > 0; k2 >>= 1) {
      if (tid < k2) red[tid] += red[tid + k2];
      __syncthreads();
    }
    if (tid == 0) {
      out[0] = (float)(-red[0] / (double)M);
      __hip_atomic_store(&g_ctr, 0, __ATOMIC_RELAXED,
                         __HIP_MEMORY_SCOPE_AGENT);  // restore for next replay
    }
  }
}

extern "C" void kernel_launch(void* const* d_in, const int* in_sizes, int n_in,
                              void* d_out, int out_size, void* d_ws, size_t ws_size,
                              hipStream_t stream) {
  const float* u   = (const float*)d_in[0];
  const float* v   = (const float*)d_in[1];
  const float* eps = (const float*)d_in[2];
  const float* I   = (const float*)d_in[3];
  const float* W   = (const float*)d_in[4];
  const float* sb  = (const float*)d_in[5];
  const float* sn  = (const float*)d_in[6];
  const float* dd  = (const float*)d_in[7];
  const float* r   = (const float*)d_in[8];
  const int M  = in_sizes[0];
  const int nb = (M + PPB - 1) / PPB;   // 1954 for M=250000 (g_part holds 2048)
  hipLaunchKernelGGL(fused_kernel, dim3(nb), dim3(TPB), 0, stream,
                     u, v, eps, I, W, sb, sn, dd, r, (float*)d_out, M, nb);
}

// Round 13
// 106.925 us; speedup vs baseline: 1.0456x; 1.0456x over previous
//
#include <hip/hip_runtime.h>
#include <math.h>

// BIMM2D: M=250000 points, P=4 interior phases, K=6 interface pairs, N_MC=64
#define KN 384            // K * N_MC table entries
#define TPB 256

// Device-global scratch. g_ctr is module-init 0 and self-restored by the last
// block each launch -> graph-replay safe, independent of d_ws poison.
__device__ float  g_tx[KN], g_ty[KN], g_tz[KN];   // SoA table (read via s_load)
__device__ float  g_hdr[12];                      // folded constants
__device__ double g_part[1024];
__device__ int    g_ctr = 0;

__device__ __forceinline__ float fexp2(float x) {
  return __builtin_amdgcn_exp2f(x);   // native v_exp_f32
}

// ---------------------------------------------------------------------------
// Prep kernel (1 block, 384 threads): builds the exp2-folded table + header
// in GLOBAL memory so the main kernel can read it through the SCALAR pipe.
// g_hdr = { isn*SQH, inv_s2*LOG2E, cq[4], wint[4], - , - }
// g_tx = In/sn*SQH, g_ty = (2G/s2)*log2e, g_tz = wk*exp(-G^2/s2)/G
// ---------------------------------------------------------------------------
__global__ __launch_bounds__(KN) void prep_kernel(
    const float* __restrict__ eps, const float* __restrict__ I,
    const float* __restrict__ W, const float* __restrict__ sb_,
    const float* __restrict__ sn_, const float* __restrict__ d_,
    const float* __restrict__ r_) {
  const int t = threadIdx.x;
  const float sb  = sb_[0];
  const float sn  = sn_[0];
  const float dd  = d_[0];
  const float rho = tanhf(r_[0]);
  const float s2  = sn * sn * (1.f - rho);      // sr^2
  const float sr  = sqrtf(s2);
  const float isn = 1.f / sn;
  const float inv_s2 = 1.f / s2;
  const float LOG2E = 1.4426950408889634f;
  const float SQH   = sqrtf(0.5f * LOG2E);

  float wmax = W[0];
  for (int j = 1; j < 10; ++j) wmax = fmaxf(wmax, W[j]);
  float se = 0.f;
  for (int j = 0; j < 10; ++j) se += expf(W[j] - wmax);
  const float lse = wmax + logf(se);

  const float LOG2PI_ = 1.8378770664093453f;
  const float LOG2_   = 0.6931471805599453f;
  const float LGG32   = -0.12078223763524522f;  // log(gamma(1.5))
  const float LOGPI_  = 1.1447298858494002f;
  const float Cterm = -logf(sn) - 0.5f * LOG2PI_ - logf(sr) - 0.5f * LOGPI_;
  const float Cint0 = LOG2_ - LGG32 - 3.f * logf(sr) - logf(sn) - 0.5f * LOG2PI_;

  if (t < 12) {
    float h = 0.f;
    if      (t == 0) h = isn * SQH;
    else if (t == 1) h = inv_s2 * LOG2E;
    else if (t < 6)  h = I[t - 2] * isn * SQH;          // cq[0..3]
    else if (t < 10) h = expf(W[t - 6] - lse + Cint0);  // wint[0..3]
    g_hdr[t] = h;
  }

  const int IAc[6] = {0, 0, 0, 1, 1, 2};
  const int IBc[6] = {1, 2, 3, 2, 3, 3};
  const int k = t >> 6;
  const float Ia = I[IAc[k]], Ib = I[IBc[k]];
  const float wk = expf(W[4 + k] - lse + Cterm) * (1.0f / 64.0f);
  const float e  = eps[t];
  const float x  = e * 2.f * dd * sb - dd * sb;
  const float y  = x / (1.4142135623730951f * sb);
  const float In = (erff(y) + 1.f) * 0.5f * (Ib - Ia) + Ia;
  const float qq = 2.f * (In - Ia) / (Ib - Ia) - 1.f;
  const float gi = erfinvf(qq);
  const float G  = (Ib - Ia) * 0.3989422804014327f / sb * expf(-gi * gi);
  g_tx[t] = In * isn * SQH;
  g_ty[t] = 2.f * inv_s2 * G * LOG2E;
  g_tz[t] = wk * expf(-G * G * inv_s2) / G;
}

// ---------------------------------------------------------------------------
// Main kernel: 1 point/thread. Inner loop reads the table through the SCALAR
// pipe (loop-uniform addresses on distinct __device__ globals -> s_load
// batches): zero ds_read, zero VMEM in the loop. Each ENT VALU instruction
// reads exactly one SGPR operand (legal). LDS pipe retired from the hot path
// (R12 analysis: broadcast ds_reads occupied ~22us/CU of the LDS pipe and the
// cross-pipe dependency chain left both pipes half-idle).
// ---------------------------------------------------------------------------
__global__ __launch_bounds__(TPB) void main_kernel(
    const float* __restrict__ u, const float* __restrict__ v,
    float* __restrict__ out, int M, int nb) {
  __shared__ double red[TPB];
  __shared__ int    slast;
  const int tid = threadIdx.x;
  const int i   = blockIdx.x * TPB + tid;

  float uu = 0.f, vv = 1.f;
  if (i < M) { uu = u[i]; vv = v[i]; }

  // header via scalar loads (uniform)
  const float husc = g_hdr[0];   // isn*SQH
  const float hg   = g_hdr[1];   // inv_s2*LOG2E

  // per-point prelude: acc = c1 + c0*S; pad threads c0=0, c1=1
  const float us = uu * husc;
  const float gg = fexp2(-vv * vv * hg);
  float aint = 0.f;
#pragma unroll
  for (int p = 0; p < 4; ++p) {
    const float dq = us - g_hdr[2 + p];
    aint = fmaf(g_hdr[6 + p], fexp2(-dq * dq), aint);
  }
  const float c0 = (i < M) ? vv * gg : 0.f;
  const float c1 = (i < M) ? vv * vv * gg * aint : 1.f;

  // ---- main loop: 48 groups of 8 entries, table via s_load ----
  float S0 = 0.f, S1 = 0.f, S2 = 0.f, S3 = 0.f;
  float S4 = 0.f, S5 = 0.f, S6 = 0.f, S7 = 0.f;
#define ENT(TX, TY, TZ, S)                         \
  {                                                \
    const float du = us - (TX);                    \
    const float nd = du * -du;                     \
    const float a1 = fmaf(vv, (TY), nd);           \
    const float a2 = fmaf(vv, -(TY), nd);          \
    S = fmaf((TZ), fexp2(a1), S);                  \
    S = fmaf(-(TZ), fexp2(a2), S);                 \
  }
  for (int g = 0; g < KN / 8; ++g) {
    const int b = g * 8;
    float X[8], Y[8], Z[8];
#pragma unroll
    for (int j = 0; j < 8; ++j) {     // -> s_load_dwordx8 x3
      X[j] = g_tx[b + j];
      Y[j] = g_ty[b + j];
      Z[j] = g_tz[b + j];
    }
    ENT(X[0], Y[0], Z[0], S0) ENT(X[1], Y[1], Z[1], S1)
    ENT(X[2], Y[2], Z[2], S2) ENT(X[3], Y[3], Z[3], S3)
    ENT(X[4], Y[4], Z[4], S4) ENT(X[5], Y[5], Z[5], S5)
    ENT(X[6], Y[6], Z[6], S6) ENT(X[7], Y[7], Z[7], S7)
  }
#undef ENT
  const float S = ((S0 + S1) + (S2 + S3)) + ((S4 + S5) + (S6 + S7));

  // per-point log-likelihood (pad threads: log(1) = 0)
  double mysum = (double)__logf(fmaf(c0, S, c1));

  // ---- block reduction (deterministic tree) ----
  red[tid] = mysum;
  __syncthreads();
  for (int s = TPB / 2; s > 0; s >>= 1) {
    if (tid < s) red[tid] += red[tid + s];
    __syncthreads();
  }
  if (tid == 0)
    __hip_atomic_store(&g_part[blockIdx.x], red[0], __ATOMIC_RELAXED,
                       __HIP_MEMORY_SCOPE_AGENT);

  // ---- last-block-done final reduction (fixed order -> deterministic) ----
  if (tid == 0) {
    const int c = __hip_atomic_fetch_add(&g_ctr, 1, __ATOMIC_ACQ_REL,
                                         __HIP_MEMORY_SCOPE_AGENT);
    slast = (c == nb - 1) ? 1 : 0;
  }
  __syncthreads();
  if (slast) {
    double s = 0.0;
    for (int j = tid; j < nb; j += TPB)
      s += __hip_atomic_load(&g_part[j], __ATOMIC_RELAXED,
                             __HIP_MEMORY_SCOPE_AGENT);
    red[tid] = s;
    __syncthreads();
    for (int k2 = TPB / 2; k2 > 0; k2 >>= 1) {
      if (tid < k2) red[tid] += red[tid + k2];
      __syncthreads();
    }
    if (tid == 0) {
      out[0] = (float)(-red[0] / (double)M);
      __hip_atomic_store(&g_ctr, 0, __ATOMIC_RELAXED,
                         __HIP_MEMORY_SCOPE_AGENT);  // restore for next replay
    }
  }
}

extern "C" void kernel_launch(void* const* d_in, const int* in_sizes, int n_in,
                              void* d_out, int out_size, void* d_ws, size_t ws_size,
                              hipStream_t stream) {
  const float* u   = (const float*)d_in[0];
  const float* v   = (const float*)d_in[1];
  const float* eps = (const float*)d_in[2];
  const float* I   = (const float*)d_in[3];
  const float* W   = (const float*)d_in[4];
  const float* sb  = (const float*)d_in[5];
  const float* sn  = (const float*)d_in[6];
  const float* dd  = (const float*)d_in[7];
  const float* r   = (const float*)d_in[8];
  const int M  = in_sizes[0];
  const int nb = (M + TPB - 1) / TPB;   // 977 for M=250000 (g_part holds 1024)

  hipLaunchKernelGGL(prep_kernel, dim3(1), dim3(KN), 0, stream,
                     eps, I, W, sb, sn, dd, r);
  hipLaunchKernelGGL(main_kernel, dim3(nb), dim3(TPB), 0, stream,
                     u, v, (float*)d_out, M, nb);
}

// Round 14
// 105.402 us; speedup vs baseline: 1.0607x; 1.0145x over previous
//
#include <hip/hip_runtime.h>
#include <math.h>

// BIMM2D: M=250000 points, P=4 interior phases, K=6 interface pairs, N_MC=64
#define KN 384            // K * N_MC table entries
#define TPB 256

// Device-global scratch. g_ctr is module-init 0 and self-restored by the last
// block each launch -> graph-replay safe, independent of d_ws poison.
__device__ float  g_tx[KN], g_ty[KN], g_tz[KN];   // SoA table (read via s_load)
__device__ float  g_hdr[12];                      // folded constants
__device__ double g_part[1024];
__device__ int    g_ctr = 0;

__device__ __forceinline__ float fexp2(float x) {
  return __builtin_amdgcn_exp2f(x);   // native v_exp_f32
}

// ---------------------------------------------------------------------------
// Prep kernel (1 block, 384 threads): builds the exp2-folded table + header
// in GLOBAL memory so the main kernel can read it through the SCALAR pipe.
// g_hdr = { isn*SQH, inv_s2*LOG2E, cq[4], wint[4], - , - }
// g_tx = In/sn*SQH, g_ty = (2G/s2)*log2e, g_tz = wk*exp(-G^2/s2)/G
// ---------------------------------------------------------------------------
__global__ __launch_bounds__(KN) void prep_kernel(
    const float* __restrict__ eps, const float* __restrict__ I,
    const float* __restrict__ W, const float* __restrict__ sb_,
    const float* __restrict__ sn_, const float* __restrict__ d_,
    const float* __restrict__ r_) {
  const int t = threadIdx.x;
  const float sb  = sb_[0];
  const float sn  = sn_[0];
  const float dd  = d_[0];
  const float rho = tanhf(r_[0]);
  const float s2  = sn * sn * (1.f - rho);      // sr^2
  const float sr  = sqrtf(s2);
  const float isn = 1.f / sn;
  const float inv_s2 = 1.f / s2;
  const float LOG2E = 1.4426950408889634f;
  const float SQH   = sqrtf(0.5f * LOG2E);

  float wmax = W[0];
  for (int j = 1; j < 10; ++j) wmax = fmaxf(wmax, W[j]);
  float se = 0.f;
  for (int j = 0; j < 10; ++j) se += expf(W[j] - wmax);
  const float lse = wmax + logf(se);

  const float LOG2PI_ = 1.8378770664093453f;
  const float LOG2_   = 0.6931471805599453f;
  const float LGG32   = -0.12078223763524522f;  // log(gamma(1.5))
  const float LOGPI_  = 1.1447298858494002f;
  const float Cterm = -logf(sn) - 0.5f * LOG2PI_ - logf(sr) - 0.5f * LOGPI_;
  const float Cint0 = LOG2_ - LGG32 - 3.f * logf(sr) - logf(sn) - 0.5f * LOG2PI_;

  if (t < 12) {
    float h = 0.f;
    if      (t == 0) h = isn * SQH;
    else if (t == 1) h = inv_s2 * LOG2E;
    else if (t < 6)  h = I[t - 2] * isn * SQH;          // cq[0..3]
    else if (t < 10) h = expf(W[t - 6] - lse + Cint0);  // wint[0..3]
    g_hdr[t] = h;
  }

  const int IAc[6] = {0, 0, 0, 1, 1, 2};
  const int IBc[6] = {1, 2, 3, 2, 3, 3};
  const int k = t >> 6;
  const float Ia = I[IAc[k]], Ib = I[IBc[k]];
  const float wk = expf(W[4 + k] - lse + Cterm) * (1.0f / 64.0f);
  const float e  = eps[t];
  const float x  = e * 2.f * dd * sb - dd * sb;
  const float y  = x / (1.4142135623730951f * sb);
  const float In = (erff(y) + 1.f) * 0.5f * (Ib - Ia) + Ia;
  const float qq = 2.f * (In - Ia) / (Ib - Ia) - 1.f;
  const float gi = erfinvf(qq);
  const float G  = (Ib - Ia) * 0.3989422804014327f / sb * expf(-gi * gi);
  g_tx[t] = In * isn * SQH;
  g_ty[t] = 2.f * inv_s2 * G * LOG2E;
  g_tz[t] = wk * expf(-G * G * inv_s2) / G;
}

// ---------------------------------------------------------------------------
// Main kernel: 1 point/thread, table via scalar pipe (R13), PLUS a 6x-unrolled
// group loop. R13's runtime loop forced s_waitcnt on 3 s_load_dwordx8 inside
// EVERY 8-entry group with no cross-group window (VGPR 20 = minimal serial
// body). Unroll 6 exposes 18 scalar loads + 48 ENT bodies per scheduling
// region so the compiler can batch/hoist s_loads groups ahead and interleave
// the 8 independent accumulator chains.
// ---------------------------------------------------------------------------
__global__ __launch_bounds__(TPB, 4) void main_kernel(
    const float* __restrict__ u, const float* __restrict__ v,
    float* __restrict__ out, int M, int nb) {
  __shared__ double red[TPB];
  __shared__ int    slast;
  const int tid = threadIdx.x;
  const int i   = blockIdx.x * TPB + tid;

  float uu = 0.f, vv = 1.f;
  if (i < M) { uu = u[i]; vv = v[i]; }

  // header via scalar loads (uniform)
  const float husc = g_hdr[0];   // isn*SQH
  const float hg   = g_hdr[1];   // inv_s2*LOG2E

  // per-point prelude: acc = c1 + c0*S; pad threads c0=0, c1=1
  const float us = uu * husc;
  const float gg = fexp2(-vv * vv * hg);
  float aint = 0.f;
#pragma unroll
  for (int p = 0; p < 4; ++p) {
    const float dq = us - g_hdr[2 + p];
    aint = fmaf(g_hdr[6 + p], fexp2(-dq * dq), aint);
  }
  const float c0 = (i < M) ? vv * gg : 0.f;
  const float c1 = (i < M) ? vv * vv * gg * aint : 1.f;

  // ---- main loop: 48 groups of 8 entries, table via s_load, unroll 6 ----
  float S0 = 0.f, S1 = 0.f, S2 = 0.f, S3 = 0.f;
  float S4 = 0.f, S5 = 0.f, S6 = 0.f, S7 = 0.f;
#define ENT(TX, TY, TZ, S)                         \
  {                                                \
    const float du = us - (TX);                    \
    const float nd = du * -du;                     \
    const float a1 = fmaf(vv, (TY), nd);           \
    const float a2 = fmaf(vv, -(TY), nd);          \
    S = fmaf((TZ), fexp2(a1), S);                  \
    S = fmaf(-(TZ), fexp2(a2), S);                 \
  }
#pragma unroll 6
  for (int g = 0; g < KN / 8; ++g) {
    const int b = g * 8;
    float X[8], Y[8], Z[8];
#pragma unroll
    for (int j = 0; j < 8; ++j) {     // -> s_load_dwordx8 x3 per group
      X[j] = g_tx[b + j];
      Y[j] = g_ty[b + j];
      Z[j] = g_tz[b + j];
    }
    ENT(X[0], Y[0], Z[0], S0) ENT(X[1], Y[1], Z[1], S1)
    ENT(X[2], Y[2], Z[2], S2) ENT(X[3], Y[3], Z[3], S3)
    ENT(X[4], Y[4], Z[4], S4) ENT(X[5], Y[5], Z[5], S5)
    ENT(X[6], Y[6], Z[6], S6) ENT(X[7], Y[7], Z[7], S7)
  }
#undef ENT
  const float S = ((S0 + S1) + (S2 + S3)) + ((S4 + S5) + (S6 + S7));

  // per-point log-likelihood (pad threads: log(1) = 0)
  double mysum = (double)__logf(fmaf(c0, S, c1));

  // ---- block reduction (deterministic tree) ----
  red[tid] = mysum;
  __syncthreads();
  for (int s = TPB / 2; s > 0; s >>= 1) {
    if (tid < s) red[tid] += red[tid + s];
    __syncthreads();
  }
  if (tid == 0)
    __hip_atomic_store(&g_part[blockIdx.x], red[0], __ATOMIC_RELAXED,
                       __HIP_MEMORY_SCOPE_AGENT);

  // ---- last-block-done final reduction (fixed order -> deterministic) ----
  if (tid == 0) {
    const int c = __hip_atomic_fetch_add(&g_ctr, 1, __ATOMIC_ACQ_REL,
                                         __HIP_MEMORY_SCOPE_AGENT);
    slast = (c == nb - 1) ? 1 : 0;
  }
  __syncthreads();
  if (slast) {
    double s = 0.0;
    for (int j = tid; j < nb; j += TPB)
      s += __hip_atomic_load(&g_part[j], __ATOMIC_RELAXED,
                             __HIP_MEMORY_SCOPE_AGENT);
    red[tid] = s;
    __syncthreads();
    for (int k2 = TPB / 2; k2 > 0; k2 >>= 1) {
      if (tid < k2) red[tid] += red[tid + k2];
      __syncthreads();
    }
    if (tid == 0) {
      out[0] = (float)(-red[0] / (double)M);
      __hip_atomic_store(&g_ctr, 0, __ATOMIC_RELAXED,
                         __HIP_MEMORY_SCOPE_AGENT);  // restore for next replay
    }
  }
}

extern "C" void kernel_launch(void* const* d_in, const int* in_sizes, int n_in,
                              void* d_out, int out_size, void* d_ws, size_t ws_size,
                              hipStream_t stream) {
  const float* u   = (const float*)d_in[0];
  const float* v   = (const float*)d_in[1];
  const float* eps = (const float*)d_in[2];
  const float* I   = (const float*)d_in[3];
  const float* W   = (const float*)d_in[4];
  const float* sb  = (const float*)d_in[5];
  const float* sn  = (const float*)d_in[6];
  const float* dd  = (const float*)d_in[7];
  const float* r   = (const float*)d_in[8];
  const int M  = in_sizes[0];
  const int nb = (M + TPB - 1) / TPB;   // 977 for M=250000 (g_part holds 1024)

  hipLaunchKernelGGL(prep_kernel, dim3(1), dim3(KN), 0, stream,
                     eps, I, W, sb, sn, dd, r);
  hipLaunchKernelGGL(main_kernel, dim3(nb), dim3(TPB), 0, stream,
                     u, v, (float*)d_out, M, nb);
}

// Round 15
// 104.307 us; speedup vs baseline: 1.0718x; 1.0105x over previous
//
#include <hip/hip_runtime.h>
#include <math.h>

// BIMM2D: M=250000 points, P=4 interior phases, K=6 interface pairs, N_MC=64
#define KN 384            // K * N_MC table entries
#define TPB 256

// Device-global scratch. g_ctr is module-init 0 and self-restored by the last
// block each launch -> graph-replay safe, independent of d_ws poison.
__device__ float  g_tx[KN], g_ty[KN], g_tz[KN];   // SoA table (read via s_load)
__device__ float  g_hdr[12];                      // folded constants
__device__ double g_part[1024];
__device__ int    g_ctr = 0;

__device__ __forceinline__ float fexp2(float x) {
  return __builtin_amdgcn_exp2f(x);   // native v_exp_f32
}

// ---------------------------------------------------------------------------
// Prep kernel (1 block, 384 threads): exp2-folded table + header in GLOBAL
// memory; main kernel reads it through the scalar pipe.
// g_hdr = { isn*SQH, inv_s2*LOG2E, cq[4], wint[4], -, - }
// g_tx = In/sn*SQH, g_ty = (2G/s2)*log2e, g_tz = wk*exp(-G^2/s2)/G
// ---------------------------------------------------------------------------
__global__ __launch_bounds__(KN) void prep_kernel(
    const float* __restrict__ eps, const float* __restrict__ I,
    const float* __restrict__ W, const float* __restrict__ sb_,
    const float* __restrict__ sn_, const float* __restrict__ d_,
    const float* __restrict__ r_) {
  const int t = threadIdx.x;
  const float sb  = sb_[0];
  const float sn  = sn_[0];
  const float dd  = d_[0];
  const float rho = tanhf(r_[0]);
  const float s2  = sn * sn * (1.f - rho);      // sr^2
  const float sr  = sqrtf(s2);
  const float isn = 1.f / sn;
  const float inv_s2 = 1.f / s2;
  const float LOG2E = 1.4426950408889634f;
  const float SQH   = sqrtf(0.5f * LOG2E);

  float wmax = W[0];
  for (int j = 1; j < 10; ++j) wmax = fmaxf(wmax, W[j]);
  float se = 0.f;
  for (int j = 0; j < 10; ++j) se += expf(W[j] - wmax);
  const float lse = wmax + logf(se);

  const float LOG2PI_ = 1.8378770664093453f;
  const float LOG2_   = 0.6931471805599453f;
  const float LGG32   = -0.12078223763524522f;  // log(gamma(1.5))
  const float LOGPI_  = 1.1447298858494002f;
  const float Cterm = -logf(sn) - 0.5f * LOG2PI_ - logf(sr) - 0.5f * LOGPI_;
  const float Cint0 = LOG2_ - LGG32 - 3.f * logf(sr) - logf(sn) - 0.5f * LOG2PI_;

  if (t < 12) {
    float h = 0.f;
    if      (t == 0) h = isn * SQH;
    else if (t == 1) h = inv_s2 * LOG2E;
    else if (t < 6)  h = I[t - 2] * isn * SQH;          // cq[0..3]
    else if (t < 10) h = expf(W[t - 6] - lse + Cint0);  // wint[0..3]
    g_hdr[t] = h;
  }

  const int IAc[6] = {0, 0, 0, 1, 1, 2};
  const int IBc[6] = {1, 2, 3, 2, 3, 3};
  const int k = t >> 6;
  const float Ia = I[IAc[k]], Ib = I[IBc[k]];
  const float wk = expf(W[4 + k] - lse + Cterm) * (1.0f / 64.0f);
  const float e  = eps[t];
  const float x  = e * 2.f * dd * sb - dd * sb;
  const float y  = x / (1.4142135623730951f * sb);
  const float In = (erff(y) + 1.f) * 0.5f * (Ib - Ia) + Ia;
  const float qq = 2.f * (In - Ia) / (Ib - Ia) - 1.f;
  const float gi = erfinvf(qq);
  const float G  = (Ib - Ia) * 0.3989422804014327f / sb * expf(-gi * gi);
  g_tx[t] = In * isn * SQH;
  g_ty[t] = 2.f * inv_s2 * G * LOG2E;
  g_tz[t] = wk * expf(-G * G * inv_s2) / G;
}

// ---------------------------------------------------------------------------
// Main kernel (R15): TWO points/thread (i, i+H) sharing every SGPR table
// entry. R11-R14 falsified LDS-latency / TLP / load-mechanism / scheduling-
// window theories; busy-time ~20-26us is invariant (VALU+trans share the
// issue slot, ~28cy/entry/wave). The remaining recoverable term is idle from
// a too-small per-wave independent-op pool: 2 pts/thread doubles in-flight
// exp chains (16 per group) and halves per-entry s_load/loop overhead, at the
// cost of wave count (1953; intra-wave ILP replaces TLP per R12's evidence).
// ---------------------------------------------------------------------------
__global__ __launch_bounds__(TPB, 4) void main_kernel(
    const float* __restrict__ u, const float* __restrict__ v,
    float* __restrict__ out, int M, int H, int nb) {
  __shared__ double red[TPB];
  __shared__ int    slast;
  const int tid = threadIdx.x;
  const int i0  = blockIdx.x * TPB + tid;
  const int i1  = i0 + H;
  const bool a0 = i0 < H;            // point 0 active (i0 < H <= M)
  const bool a1 = a0 && (i1 < M);    // point 1 active

  float u0 = 0.f, v0 = 1.f, u1 = 0.f, v1 = 1.f;
  if (a0) { u0 = u[i0]; v0 = v[i0]; }
  if (a1) { u1 = u[i1]; v1 = v[i1]; }

  // header via scalar loads (uniform)
  const float husc = g_hdr[0];   // isn*SQH
  const float hg   = g_hdr[1];   // inv_s2*LOG2E

  // per-point prelude: acc = c1 + c0*S; inactive -> c0=0, c1=1 (log 1 = 0)
  const float us0 = u0 * husc,  us1 = u1 * husc;
  const float gg0 = fexp2(-v0 * v0 * hg);
  const float gg1 = fexp2(-v1 * v1 * hg);
  float ai0 = 0.f, ai1 = 0.f;
#pragma unroll
  for (int p = 0; p < 4; ++p) {
    const float cqp = g_hdr[2 + p], wip = g_hdr[6 + p];
    const float d0 = us0 - cqp, d1 = us1 - cqp;
    ai0 = fmaf(wip, fexp2(-d0 * d0), ai0);
    ai1 = fmaf(wip, fexp2(-d1 * d1), ai1);
  }
  const float c00 = a0 ? v0 * gg0 : 0.f;
  const float c10 = a0 ? v0 * v0 * gg0 * ai0 : 1.f;
  const float c01 = a1 ? v1 * gg1 : 0.f;
  const float c11 = a1 ? v1 * v1 * gg1 * ai1 : 1.f;

  // ---- main loop: 48 groups of 8 entries, s_load table, both points ----
  float S0 = 0.f, S1 = 0.f, S2 = 0.f, S3 = 0.f;   // point 0
  float T0 = 0.f, T1 = 0.f, T2 = 0.f, T3 = 0.f;   // point 1
#define ENT2(TX, TY, TZ, S, T)                     \
  {                                                \
    const float dA = us0 - (TX);                   \
    const float nA = dA * -dA;                     \
    const float xA = fmaf(v0, (TY), nA);           \
    const float yA = fmaf(v0, -(TY), nA);          \
    S = fmaf((TZ), fexp2(xA), S);                  \
    S = fmaf(-(TZ), fexp2(yA), S);                 \
    const float dB = us1 - (TX);                   \
    const float nB = dB * -dB;                     \
    const float xB = fmaf(v1, (TY), nB);           \
    const float yB = fmaf(v1, -(TY), nB);          \
    T = fmaf((TZ), fexp2(xB), T);                  \
    T = fmaf(-(TZ), fexp2(yB), T);                 \
  }
#pragma unroll 6
  for (int g = 0; g < KN / 8; ++g) {
    const int b = g * 8;
    float X[8], Y[8], Z[8];
#pragma unroll
    for (int j = 0; j < 8; ++j) {     // -> s_load_dwordx8 x3 per group
      X[j] = g_tx[b + j];
      Y[j] = g_ty[b + j];
      Z[j] = g_tz[b + j];
    }
    ENT2(X[0], Y[0], Z[0], S0, T0) ENT2(X[1], Y[1], Z[1], S1, T1)
    ENT2(X[2], Y[2], Z[2], S2, T2) ENT2(X[3], Y[3], Z[3], S3, T3)
    ENT2(X[4], Y[4], Z[4], S0, T0) ENT2(X[5], Y[5], Z[5], S1, T1)
    ENT2(X[6], Y[6], Z[6], S2, T2) ENT2(X[7], Y[7], Z[7], S3, T3)
  }
#undef ENT2
  const float SA = (S0 + S1) + (S2 + S3);
  const float SB = (T0 + T1) + (T2 + T3);

  // per-point log-likelihoods (inactive -> log(1) = 0)
  double mysum = (double)__logf(fmaf(c00, SA, c10))
               + (double)__logf(fmaf(c01, SB, c11));

  // ---- block reduction (deterministic tree) ----
  red[tid] = mysum;
  __syncthreads();
  for (int s = TPB / 2; s > 0; s >>= 1) {
    if (tid < s) red[tid] += red[tid + s];
    __syncthreads();
  }
  if (tid == 0)
    __hip_atomic_store(&g_part[blockIdx.x], red[0], __ATOMIC_RELAXED,
                       __HIP_MEMORY_SCOPE_AGENT);

  // ---- last-block-done final reduction (fixed order -> deterministic) ----
  if (tid == 0) {
    const int c = __hip_atomic_fetch_add(&g_ctr, 1, __ATOMIC_ACQ_REL,
                                         __HIP_MEMORY_SCOPE_AGENT);
    slast = (c == nb - 1) ? 1 : 0;
  }
  __syncthreads();
  if (slast) {
    double s = 0.0;
    for (int j = tid; j < nb; j += TPB)
      s += __hip_atomic_load(&g_part[j], __ATOMIC_RELAXED,
                             __HIP_MEMORY_SCOPE_AGENT);
    red[tid] = s;
    __syncthreads();
    for (int k2 = TPB / 2; k2 > 0; k2 >>= 1) {
      if (tid < k2) red[tid] += red[tid + k2];
      __syncthreads();
    }
    if (tid == 0) {
      out[0] = (float)(-red[0] / (double)M);
      __hip_atomic_store(&g_ctr, 0, __ATOMIC_RELAXED,
                         __HIP_MEMORY_SCOPE_AGENT);  // restore for next replay
    }
  }
}

extern "C" void kernel_launch(void* const* d_in, const int* in_sizes, int n_in,
                              void* d_out, int out_size, void* d_ws, size_t ws_size,
                              hipStream_t stream) {
  const float* u   = (const float*)d_in[0];
  const float* v   = (const float*)d_in[1];
  const float* eps = (const float*)d_in[2];
  const float* I   = (const float*)d_in[3];
  const float* W   = (const float*)d_in[4];
  const float* sb  = (const float*)d_in[5];
  const float* sn  = (const float*)d_in[6];
  const float* dd  = (const float*)d_in[7];
  const float* r   = (const float*)d_in[8];
  const int M  = in_sizes[0];
  const int H  = (M + 1) / 2;               // pair (i, i+H)
  const int nb = (H + TPB - 1) / TPB;       // 489 for M=250000

  hipLaunchKernelGGL(prep_kernel, dim3(1), dim3(KN), 0, stream,
                     eps, I, W, sb, sn, dd, r);
  hipLaunchKernelGGL(main_kernel, dim3(nb), dim3(TPB), 0, stream,
                     u, v, (float*)d_out, M, H, nb);
}